// Round 4
// baseline (265.457 us; speedup 1.0000x reference)
//
#include <hip/hip_runtime.h>

typedef unsigned short u16;
typedef unsigned int u32;
typedef short bf16x8 __attribute__((ext_vector_type(8)));
typedef float f32x4 __attribute__((ext_vector_type(4)));

#define AS_GLOBAL __attribute__((address_space(1)))
#define AS_LDS __attribute__((address_space(3)))

__device__ __forceinline__ void async16(const void* g, void* l) {
  __builtin_amdgcn_global_load_lds((const AS_GLOBAL u32*)g, (AS_LDS u32*)l, 16, 0, 0);
}

__device__ __forceinline__ u16 f2bf(float f) {
  u32 u = __builtin_bit_cast(u32, f);
  u += 0x7FFFu + ((u >> 16) & 1u);   // RNE
  return (u16)(u >> 16);
}

__device__ __forceinline__ u32 pk2bf(float lo, float hi) {
  return __builtin_amdgcn_perm(__builtin_bit_cast(u32, hi),
                               __builtin_bit_cast(u32, lo), 0x07060302u);
}

__device__ __forceinline__ float fexp2(float x) {
#if __has_builtin(__builtin_amdgcn_exp2f)
  return __builtin_amdgcn_exp2f(x);
#else
  return exp2f(x);
#endif
}

// ---------------- Pass A: all four f32 -> bf16 converts in one launch ----------------
__global__ __launch_bounds__(256) void cvt_all(const float* __restrict__ x,
                                               const float* __restrict__ wq,
                                               const float* __restrict__ wk,
                                               const float* __restrict__ wv,
                                               u16* __restrict__ xb,
                                               u16* __restrict__ wb) {
  const int blk = blockIdx.x;
  const float* src;
  u16* dst;
  int i;
  if (blk < 8192) {
    src = x; dst = xb; i = blk * 256 + threadIdx.x;
  } else if (blk < 9216) {
    src = wq; dst = wb; i = (blk - 8192) * 256 + threadIdx.x;
  } else if (blk < 10240) {
    src = wk; dst = wb + 1048576; i = (blk - 9216) * 256 + threadIdx.x;
  } else {
    src = wv; dst = wb + 2097152; i = (blk - 10240) * 256 + threadIdx.x;
  }
  float4 f = reinterpret_cast<const float4*>(src)[i];
  ushort4 o;
  o.x = f2bf(f.x); o.y = f2bf(f.y); o.z = f2bf(f.z); o.w = f2bf(f.w);
  reinterpret_cast<ushort4*>(dst)[i] = o;
}

// ---------------- Pass B: QKV projection GEMM (C = X * W^T), double-buffered ----------------
// grid: x = m-tile (64), y = n-tile (8), z = matrix (3)
// z=0 (Q), z=1 (K): out [B][H][T][64]; z=2 (V): out TRANSPOSED [B][H][64][T]
__global__ __launch_bounds__(256, 3) void qkv_gemm(const u16* __restrict__ X,
                                                   const u16* __restrict__ W,
                                                   u16* __restrict__ O) {
  const int z = blockIdx.z;
  const u16* Wz = W + (size_t)z * (1024 * 1024);
  u16* Oz = O + (size_t)z * (8192 * 1024);

  __shared__ __align__(16) u16 As[2][128 * 32];
  __shared__ __align__(16) u16 Bs[2][128 * 32];

  const int t = threadIdx.x;
  const int lane = t & 63, w = t >> 6, quad = lane >> 4, lq = lane & 15;
  const int wm = (w >> 1) * 64, wn = (w & 1) * 64;
  const size_t m0 = (size_t)blockIdx.x * 128;
  const int n0 = blockIdx.y * 128;
  const int srow = t >> 2, sseg = (t & 3) * 8;

  f32x4 acc[4][4];
#pragma unroll
  for (int i = 0; i < 4; ++i)
#pragma unroll
    for (int j = 0; j < 4; ++j) acc[i][j] = f32x4{0.f, 0.f, 0.f, 0.f};

  const u16* ga = X + (m0 + srow) * 1024 + sseg;
  const u16* gb = Wz + (size_t)(n0 + srow) * 1024 + sseg;

  async16(ga, &As[0][srow * 32 + sseg]);
  async16(ga + 64 * 1024, &As[0][(64 + srow) * 32 + sseg]);
  async16(gb, &Bs[0][srow * 32 + sseg]);
  async16(gb + 64 * 1024, &Bs[0][(64 + srow) * 32 + sseg]);

  for (int kt = 0; kt < 32; ++kt) {
    const int cur = kt & 1;
    __syncthreads();
    if (kt < 31) {
      const int k1 = (kt + 1) * 32;
      async16(ga + k1, &As[cur ^ 1][srow * 32 + sseg]);
      async16(ga + 64 * 1024 + k1, &As[cur ^ 1][(64 + srow) * 32 + sseg]);
      async16(gb + k1, &Bs[cur ^ 1][srow * 32 + sseg]);
      async16(gb + 64 * 1024 + k1, &Bs[cur ^ 1][(64 + srow) * 32 + sseg]);
    }
    bf16x8 af[4], bfr[4];
#pragma unroll
    for (int i = 0; i < 4; ++i)
      af[i] = *reinterpret_cast<const bf16x8*>(&As[cur][(wm + i * 16 + lq) * 32 + quad * 8]);
#pragma unroll
    for (int j = 0; j < 4; ++j)
      bfr[j] = *reinterpret_cast<const bf16x8*>(&Bs[cur][(wn + j * 16 + lq) * 32 + quad * 8]);
#pragma unroll
    for (int i = 0; i < 4; ++i)
#pragma unroll
      for (int j = 0; j < 4; ++j)
        acc[i][j] = __builtin_amdgcn_mfma_f32_16x16x32_bf16(af[i], bfr[j], acc[i][j], 0, 0, 0);
  }

#pragma unroll
  for (int i = 0; i < 4; ++i) {
#pragma unroll
    for (int j = 0; j < 4; ++j) {
      const int n = n0 + wn + j * 16 + lq;
      const int hh = n >> 6, d = n & 63;
#pragma unroll
      for (int r = 0; r < 4; ++r) {
        const size_t m = m0 + wm + i * 16 + quad * 4 + r;
        const size_t bb = m >> 11, tt = m & 2047;
        if (z != 2)
          Oz[((bb * 16 + hh) * 2048 + tt) * 64 + d] = f2bf(acc[i][j][r]);
        else
          Oz[((bb * 16 + hh) * 64 + d) * 2048 + tt] = f2bf(acc[i][j][r]);
      }
    }
  }
}

// ---------------- Pass C: flash attention, S^T-form, fixed-max softmax ----------------
// grid: x = b*16+h (64) [XCD locality: 8 heads/XCD, K+V 4MB L2-resident], y = q-tile (8)
// Block = 4 waves; each wave owns 64 q-rows (4 qgroups of 16). 64-key tiles, K/V dbuf.
__global__ __launch_bounds__(256, 2) void palace_attn(const u16* __restrict__ Q,
                                                      const u16* __restrict__ K,
                                                      const u16* __restrict__ Vt,
                                                      float* __restrict__ out,
                                                      const float* __restrict__ wptr) {
  const int bh = blockIdx.x, qt = blockIdx.y;
  const int h = bh & 15, b = bh >> 4;
  const size_t base = (size_t)bh * (2048 * 64);

  __shared__ __align__(16) u16 Ks[2][64 * 64];   // [key][d], XOR-swizzled 16B chunks
  __shared__ __align__(16) u16 Vs[2][64 * 64];   // [d][key], XOR-swizzled 16B chunks
  __shared__ __align__(16) u16 Ps[4][64 * 64];   // per-wave P [q][key], XOR-swizzled

  const int t = threadIdx.x;
  const int w = t >> 6, lane = t & 63, quad = lane >> 4, lq = lane & 15;
  const int q1 = quad >> 1, q0 = quad & 1, x7 = lq & 7;
  const float sig = 1.f / (1.f + __expf(-wptr[0]));
  const float Ci = 0.125f * 1.44269504f;   // intra coeff (scale * log2 e)
  const float Co = Ci * sig;               // inter coeff
  const float MC = 14.4269504f;            // fixed softmax offset: 10 * log2 e

  // palace mask: q palace-slot (mod 64) = qg*2 + (lq>>3); key slot = kg*2 + q1.
  // equal iff kg==qg && (lq>>3)==q1 -> per-lane diag coeff:
  const float Cd = ((lq >> 3) == q1) ? Ci : Co;

  // Q B-frags in registers: B[k=d][n=q]
  bf16x8 qf[4][2];
#pragma unroll
  for (int qg = 0; qg < 4; ++qg)
#pragma unroll
    for (int kc = 0; kc < 2; ++kc)
      qf[qg][kc] = *reinterpret_cast<const bf16x8*>(
          Q + base + (size_t)(qt * 256 + w * 64 + qg * 16 + lq) * 64 + kc * 32 + quad * 8);

  // staging offsets: slot = r*256+t; row = slot>>3; logical chunk = (slot&7) ^ (row&7)
  int ko[2], vo[2];
#pragma unroll
  for (int r = 0; r < 2; ++r) {
    const int slot = r * 256 + t;
    const int row = slot >> 3;
    const int cl = (slot & 7) ^ (row & 7);
    ko[r] = row * 64 + cl * 8;     // K: [key][64]
    vo[r] = row * 2048 + cl * 8;   // Vt: [d][2048]
  }

  f32x4 O[4][4];
  float lsum[4] = {0.f, 0.f, 0.f, 0.f};
#pragma unroll
  for (int qg = 0; qg < 4; ++qg)
#pragma unroll
    for (int dg = 0; dg < 4; ++dg) O[qg][dg] = f32x4{0.f, 0.f, 0.f, 0.f};

  // prologue: stage tile 0 into buffer 0
  {
    const u16* kgp = K + base;
    const u16* vgp = Vt + base;
    async16(kgp + ko[0], &Ks[0][(w * 64) * 8]);
    async16(kgp + ko[1], &Ks[0][(256 + w * 64) * 8]);
    async16(vgp + vo[0], &Vs[0][(w * 64) * 8]);
    async16(vgp + vo[1], &Vs[0][(256 + w * 64) * 8]);
  }

  for (int kt = 0; kt < 32; ++kt) {
    const int cur = kt & 1;
    __syncthreads();  // drains DMA into buf[cur]; prior reads of buf[cur^1] done
    if (kt < 31) {
      const u16* kgp = K + base + (size_t)(kt + 1) * 4096;
      const u16* vgp = Vt + base + (size_t)(kt + 1) * 64;
      const int nb = cur ^ 1;
      async16(kgp + ko[0], &Ks[nb][(w * 64) * 8]);
      async16(kgp + ko[1], &Ks[nb][(256 + w * 64) * 8]);
      async16(vgp + vo[0], &Vs[nb][(w * 64) * 8]);
      async16(vgp + vo[1], &Vs[nb][(256 + w * 64) * 8]);
    }

    // S^T[key][q] = K · Q^T, then exp -> Ps, one kg (16 keys) at a time
#pragma unroll
    for (int kg = 0; kg < 4; ++kg) {
      const bf16x8 kf0 = *reinterpret_cast<const bf16x8*>(
          &Ks[cur][((kg * 16 + lq) * 8 + (quad ^ x7)) * 8]);
      const bf16x8 kf1 = *reinterpret_cast<const bf16x8*>(
          &Ks[cur][((kg * 16 + lq) * 8 + ((4 + quad) ^ x7)) * 8]);
      f32x4 s[4];
#pragma unroll
      for (int qg = 0; qg < 4; ++qg) {
        f32x4 z = {0.f, 0.f, 0.f, 0.f};
        z = __builtin_amdgcn_mfma_f32_16x16x32_bf16(kf0, qf[qg][0], z, 0, 0, 0);
        s[qg] = __builtin_amdgcn_mfma_f32_16x16x32_bf16(kf1, qf[qg][1], z, 0, 0, 0);
      }
      const int pchunk = ((kg * 2 + q1) ^ x7) * 8 + q0 * 4;
#pragma unroll
      for (int qg = 0; qg < 4; ++qg) {
        const float cf = (kg == qg) ? Cd : Co;
        float p0 = fexp2(__builtin_fmaf(s[qg][0], cf, -MC));
        float p1 = fexp2(__builtin_fmaf(s[qg][1], cf, -MC));
        float p2 = fexp2(__builtin_fmaf(s[qg][2], cf, -MC));
        float p3 = fexp2(__builtin_fmaf(s[qg][3], cf, -MC));
        lsum[qg] += (p0 + p1) + (p2 + p3);
        uint2 pk;
        pk.x = pk2bf(p0, p1);
        pk.y = pk2bf(p2, p3);
        *reinterpret_cast<uint2*>(&Ps[w][(qg * 16 + lq) * 64 + pchunk]) = pk;
      }
    }
    // per-wave scratch: order write->read within the wave, no block barrier
    __asm__ volatile("s_waitcnt lgkmcnt(0)" ::: "memory");

    // O[q][d] += P · V
#pragma unroll
    for (int dg = 0; dg < 4; ++dg) {
      const bf16x8 vf0 = *reinterpret_cast<const bf16x8*>(
          &Vs[cur][((dg * 16 + lq) * 8 + (quad ^ x7)) * 8]);
      const bf16x8 vf1 = *reinterpret_cast<const bf16x8*>(
          &Vs[cur][((dg * 16 + lq) * 8 + ((4 + quad) ^ x7)) * 8]);
#pragma unroll
      for (int qg = 0; qg < 4; ++qg) {
        const bf16x8 pf0 = *reinterpret_cast<const bf16x8*>(
            &Ps[w][(qg * 16 + lq) * 64 + ((quad) ^ x7) * 8]);
        const bf16x8 pf1 = *reinterpret_cast<const bf16x8*>(
            &Ps[w][(qg * 16 + lq) * 64 + ((4 + quad) ^ x7) * 8]);
        O[qg][dg] = __builtin_amdgcn_mfma_f32_16x16x32_bf16(pf0, vf0, O[qg][dg], 0, 0, 0);
        O[qg][dg] = __builtin_amdgcn_mfma_f32_16x16x32_bf16(pf1, vf1, O[qg][dg], 0, 0, 0);
      }
    }
  }

  float inv[4];
#pragma unroll
  for (int qg = 0; qg < 4; ++qg) {
    float l = lsum[qg];
    l += __shfl_xor(l, 16, 64);
    l += __shfl_xor(l, 32, 64);
    inv[qg] = 1.f / l;
  }

  // epilogue: O[qg][dg][r] -> out[b][t = qt*256+w*64+qg*16+quad*4+r][h*64 + dg*16 + lq]
#pragma unroll
  for (int qg = 0; qg < 4; ++qg) {
#pragma unroll
    for (int r = 0; r < 4; ++r) {
      const float iv = __shfl(inv[qg], quad * 4 + r, 64);
      const size_t trow = (size_t)(qt * 256 + w * 64 + qg * 16 + quad * 4 + r);
      float* op = out + ((size_t)b * 2048 + trow) * 1024 + h * 64 + lq;
#pragma unroll
      for (int dg = 0; dg < 4; ++dg) op[dg * 16] = O[qg][dg][r] * iv;
    }
  }
}

extern "C" void kernel_launch(void* const* d_in, const int* in_sizes, int n_in,
                              void* d_out, int out_size, void* d_ws, size_t ws_size,
                              hipStream_t stream) {
  (void)in_sizes; (void)n_in; (void)out_size; (void)ws_size;
  const float* x = (const float*)d_in[0];
  const float* Wq = (const float*)d_in[1];
  const float* Wk = (const float*)d_in[2];
  const float* Wv = (const float*)d_in[3];
  const float* wip = (const float*)d_in[4];
  float* out = (float*)d_out;

  u16* xb = (u16*)d_ws;
  u16* wb = xb + 8388608;
  u16* qb = wb + 3145728;
  u16* kb = qb + 8388608;
  u16* vb = kb + 8388608;   // holds V^T [B][H][64][2048]

  cvt_all<<<11264, 256, 0, stream>>>(x, Wq, Wk, Wv, xb, wb);
  qkv_gemm<<<dim3(64, 8, 3), 256, 0, stream>>>(xb, wb, qb);
  palace_attn<<<dim3(64, 8, 1), 256, 0, stream>>>(qb, kb, vb, out, wip);
}

// Round 6
// 252.989 us; speedup vs baseline: 1.0493x; 1.0493x over previous
//
#include <hip/hip_runtime.h>

typedef unsigned short u16;
typedef unsigned int u32;
typedef short bf16x8 __attribute__((ext_vector_type(8)));
typedef short bf16x4 __attribute__((ext_vector_type(4)));
typedef float f32x4 __attribute__((ext_vector_type(4)));
typedef u32 u32x2 __attribute__((ext_vector_type(2)));

#define AS_GLOBAL __attribute__((address_space(1)))
#define AS_LDS __attribute__((address_space(3)))

// 16x16x16 bf16 MFMA: gfx90a-lineage builtin spelling, carried forward on gfx950.
// Host pass never executes device code; stub avoids host-side builtin lookup
// (__has_builtin is unreliable for aux-target builtins on the host pass).
#if defined(__HIP_DEVICE_COMPILE__)
#define MFMA16(a, b, c) __builtin_amdgcn_mfma_f32_16x16x16bf16_1k(a, b, c, 0, 0, 0)
#else
#define MFMA16(a, b, c) (c)
#endif

__device__ __forceinline__ void async16(const void* g, void* l) {
  __builtin_amdgcn_global_load_lds((const AS_GLOBAL u32*)g, (AS_LDS u32*)l, 16, 0, 0);
}

__device__ __forceinline__ u16 f2bf(float f) {
  u32 u = __builtin_bit_cast(u32, f);
  u += 0x7FFFu + ((u >> 16) & 1u);   // RNE
  return (u16)(u >> 16);
}

__device__ __forceinline__ u32 pk2bf(float lo, float hi) {
  return __builtin_amdgcn_perm(__builtin_bit_cast(u32, hi),
                               __builtin_bit_cast(u32, lo), 0x07060302u);
}

__device__ __forceinline__ float fexp2(float x) {
#if __has_builtin(__builtin_amdgcn_exp2f)
  return __builtin_amdgcn_exp2f(x);
#else
  return exp2f(x);
#endif
}

// ---------------- Pass A: all four f32 -> bf16 converts in one launch ----------------
__global__ __launch_bounds__(256) void cvt_all(const float* __restrict__ x,
                                               const float* __restrict__ wq,
                                               const float* __restrict__ wk,
                                               const float* __restrict__ wv,
                                               u16* __restrict__ xb,
                                               u16* __restrict__ wb) {
  const int blk = blockIdx.x;
  const float* src;
  u16* dst;
  int i;
  if (blk < 8192) {
    src = x; dst = xb; i = blk * 256 + threadIdx.x;
  } else if (blk < 9216) {
    src = wq; dst = wb; i = (blk - 8192) * 256 + threadIdx.x;
  } else if (blk < 10240) {
    src = wk; dst = wb + 1048576; i = (blk - 9216) * 256 + threadIdx.x;
  } else {
    src = wv; dst = wb + 2097152; i = (blk - 10240) * 256 + threadIdx.x;
  }
  float4 f = reinterpret_cast<const float4*>(src)[i];
  ushort4 o;
  o.x = f2bf(f.x); o.y = f2bf(f.y); o.z = f2bf(f.z); o.w = f2bf(f.w);
  reinterpret_cast<ushort4*>(dst)[i] = o;
}

// ---------------- Pass B: QKV projection GEMM (C = X * W^T), double-buffered ----------------
// grid: x = m-tile (64), y = n-tile (8), z = matrix (3)
// z=0 (Q), z=1 (K): out [B][H][T][64]; z=2 (V): out TRANSPOSED [B][H][64][T]
__global__ __launch_bounds__(256, 3) void qkv_gemm(const u16* __restrict__ X,
                                                   const u16* __restrict__ W,
                                                   u16* __restrict__ O) {
  const int z = blockIdx.z;
  const u16* Wz = W + (size_t)z * (1024 * 1024);
  u16* Oz = O + (size_t)z * (8192 * 1024);

  __shared__ __align__(16) u16 As[2][128 * 32];
  __shared__ __align__(16) u16 Bs[2][128 * 32];

  const int t = threadIdx.x;
  const int lane = t & 63, w = t >> 6, quad = lane >> 4, lq = lane & 15;
  const int wm = (w >> 1) * 64, wn = (w & 1) * 64;
  const size_t m0 = (size_t)blockIdx.x * 128;
  const int n0 = blockIdx.y * 128;
  const int srow = t >> 2, sseg = (t & 3) * 8;

  f32x4 acc[4][4];
#pragma unroll
  for (int i = 0; i < 4; ++i)
#pragma unroll
    for (int j = 0; j < 4; ++j) acc[i][j] = f32x4{0.f, 0.f, 0.f, 0.f};

  const u16* ga = X + (m0 + srow) * 1024 + sseg;
  const u16* gb = Wz + (size_t)(n0 + srow) * 1024 + sseg;

  async16(ga, &As[0][srow * 32 + sseg]);
  async16(ga + 64 * 1024, &As[0][(64 + srow) * 32 + sseg]);
  async16(gb, &Bs[0][srow * 32 + sseg]);
  async16(gb + 64 * 1024, &Bs[0][(64 + srow) * 32 + sseg]);

  for (int kt = 0; kt < 32; ++kt) {
    const int cur = kt & 1;
    __syncthreads();
    if (kt < 31) {
      const int k1 = (kt + 1) * 32;
      async16(ga + k1, &As[cur ^ 1][srow * 32 + sseg]);
      async16(ga + 64 * 1024 + k1, &As[cur ^ 1][(64 + srow) * 32 + sseg]);
      async16(gb + k1, &Bs[cur ^ 1][srow * 32 + sseg]);
      async16(gb + 64 * 1024 + k1, &Bs[cur ^ 1][(64 + srow) * 32 + sseg]);
    }
    bf16x8 af[4], bfr[4];
#pragma unroll
    for (int i = 0; i < 4; ++i)
      af[i] = *reinterpret_cast<const bf16x8*>(&As[cur][(wm + i * 16 + lq) * 32 + quad * 8]);
#pragma unroll
    for (int j = 0; j < 4; ++j)
      bfr[j] = *reinterpret_cast<const bf16x8*>(&Bs[cur][(wn + j * 16 + lq) * 32 + quad * 8]);
#pragma unroll
    for (int i = 0; i < 4; ++i)
#pragma unroll
      for (int j = 0; j < 4; ++j)
        acc[i][j] = __builtin_amdgcn_mfma_f32_16x16x32_bf16(af[i], bfr[j], acc[i][j], 0, 0, 0);
  }

#pragma unroll
  for (int i = 0; i < 4; ++i) {
#pragma unroll
    for (int j = 0; j < 4; ++j) {
      const int n = n0 + wn + j * 16 + lq;
      const int hh = n >> 6, d = n & 63;
#pragma unroll
      for (int r = 0; r < 4; ++r) {
        const size_t m = m0 + wm + i * 16 + quad * 4 + r;
        const size_t bb = m >> 11, tt = m & 2047;
        if (z != 2)
          Oz[((bb * 16 + hh) * 2048 + tt) * 64 + d] = f2bf(acc[i][j][r]);
        else
          Oz[((bb * 16 + hh) * 64 + d) * 2048 + tt] = f2bf(acc[i][j][r]);
      }
    }
  }
}

// ---------------- Pass C: flash attention, S^T-form, P-in-register PV ----------------
// grid: x = b*16+h (64) [XCD locality], y = q-tile (8). Block = 4 waves, 64 q/wave.
// QK^T via 16x16x32 (S^T C-layout); PV via 16x16x16: S^T C-layout == P A-layout.
__global__ __launch_bounds__(256, 2) void palace_attn(const u16* __restrict__ Q,
                                                      const u16* __restrict__ K,
                                                      const u16* __restrict__ Vt,
                                                      float* __restrict__ out,
                                                      const float* __restrict__ wptr) {
  const int bh = blockIdx.x, qt = blockIdx.y;
  const int h = bh & 15, b = bh >> 4;
  const size_t base = (size_t)bh * (2048 * 64);

  __shared__ __align__(16) u16 Ks[2][64 * 64];   // [key][d], XOR-swizzled 16B chunks
  __shared__ __align__(16) u16 Vs[2][64 * 64];   // [d][key], XOR-swizzled 16B chunks

  const int t = threadIdx.x;
  const int w = t >> 6, lane = t & 63, quad = lane >> 4, lq = lane & 15;
  const int q1 = quad >> 1, q0 = quad & 1, x7 = lq & 7;
  const float sig = 1.f / (1.f + __expf(-wptr[0]));
  const float Ci = 0.125f * 1.44269504f;   // intra coeff (scale * log2 e)
  const float Co = Ci * sig;               // inter coeff
  const float MC = 14.4269504f;            // fixed softmax offset: 10 * log2 e

  // palace mask: q slot (mod 64) = qg*2+(lq>>3); key slot = kg*2+q1; equal iff
  // kg==qg && (lq>>3)==q1:
  const float Cd = ((lq >> 3) == q1) ? Ci : Co;

  // Q B-frags (16x16x32): B[k=d][n=q]
  bf16x8 qf[4][2];
#pragma unroll
  for (int qg = 0; qg < 4; ++qg)
#pragma unroll
    for (int kc = 0; kc < 2; ++kc)
      qf[qg][kc] = *reinterpret_cast<const bf16x8*>(
          Q + base + (size_t)(qt * 256 + w * 64 + qg * 16 + lq) * 64 + kc * 32 + quad * 8);

  // staging: slot = r*256+t; row = slot>>3; logical 16B chunk = (slot&7)^(row&7)
  int ko[2], vo[2];
#pragma unroll
  for (int r = 0; r < 2; ++r) {
    const int slot = r * 256 + t;
    const int row = slot >> 3;
    const int cl = (slot & 7) ^ (row & 7);
    ko[r] = row * 64 + cl * 8;     // K: [key][64]
    vo[r] = row * 2048 + cl * 8;   // Vt: [d][2048]
  }

  f32x4 O[4][4];
  float lsum[4] = {0.f, 0.f, 0.f, 0.f};
#pragma unroll
  for (int qg = 0; qg < 4; ++qg)
#pragma unroll
    for (int dg = 0; dg < 4; ++dg) O[qg][dg] = f32x4{0.f, 0.f, 0.f, 0.f};

  // prologue: stage tile 0 into buffer 0
  {
    const u16* kgp = K + base;
    const u16* vgp = Vt + base;
    async16(kgp + ko[0], &Ks[0][(w * 64) * 8]);
    async16(kgp + ko[1], &Ks[0][(256 + w * 64) * 8]);
    async16(vgp + vo[0], &Vs[0][(w * 64) * 8]);
    async16(vgp + vo[1], &Vs[0][(256 + w * 64) * 8]);
  }

  for (int kt = 0; kt < 32; ++kt) {
    const int cur = kt & 1;
    __syncthreads();  // drains DMA into buf[cur]; prior reads of buf[cur^1] done
    if (kt < 31) {
      const u16* kgp = K + base + (size_t)(kt + 1) * 4096;
      const u16* vgp = Vt + base + (size_t)(kt + 1) * 64;
      const int nb = cur ^ 1;
      async16(kgp + ko[0], &Ks[nb][(w * 64) * 8]);
      async16(kgp + ko[1], &Ks[nb][(256 + w * 64) * 8]);
      async16(vgp + vo[0], &Vs[nb][(w * 64) * 8]);
      async16(vgp + vo[1], &Vs[nb][(256 + w * 64) * 8]);
    }

#pragma unroll
    for (int kg = 0; kg < 4; ++kg) {
      // S^T[key][q] = K · Q^T (16x16x32): A = K-frag (m=key), B = Q-frag (n=q)
      const bf16x8 kf0 = *reinterpret_cast<const bf16x8*>(
          &Ks[cur][((kg * 16 + lq) * 8 + (quad ^ x7)) * 8]);
      const bf16x8 kf1 = *reinterpret_cast<const bf16x8*>(
          &Ks[cur][((kg * 16 + lq) * 8 + ((4 + quad) ^ x7)) * 8]);
      f32x4 s[4];
#pragma unroll
      for (int qg = 0; qg < 4; ++qg) {
        f32x4 z = {0.f, 0.f, 0.f, 0.f};
        z = __builtin_amdgcn_mfma_f32_16x16x32_bf16(kf0, qf[qg][0], z, 0, 0, 0);
        s[qg] = __builtin_amdgcn_mfma_f32_16x16x32_bf16(kf1, qf[qg][1], z, 0, 0, 0);
      }

      // V B-frags (16x16x16): B[k=key=quad*4+j][n=d=dg*16+lq] from Vs [d][key]
      const int c16 = (2 * kg + q1) ^ x7;  // swizzled 16B chunk index
      bf16x4 vb[4];
#pragma unroll
      for (int dg = 0; dg < 4; ++dg)
        vb[dg] = *reinterpret_cast<const bf16x4*>(
            &Vs[cur][(dg * 16 + lq) * 64 + c16 * 8 + q0 * 4]);

      // softmax weights + PV: P A-frag == S^T C-layout (16x16x16 identity)
#pragma unroll
      for (int qg = 0; qg < 4; ++qg) {
        const float cf = (kg == qg) ? Cd : Co;
        float p0 = fexp2(__builtin_fmaf(s[qg][0], cf, -MC));
        float p1 = fexp2(__builtin_fmaf(s[qg][1], cf, -MC));
        float p2 = fexp2(__builtin_fmaf(s[qg][2], cf, -MC));
        float p3 = fexp2(__builtin_fmaf(s[qg][3], cf, -MC));
        lsum[qg] += (p0 + p1) + (p2 + p3);
        u32x2 pk;
        pk.x = pk2bf(p0, p1);
        pk.y = pk2bf(p2, p3);
        const bf16x4 pa = __builtin_bit_cast(bf16x4, pk);
#pragma unroll
        for (int dg = 0; dg < 4; ++dg)
          O[qg][dg] = MFMA16(pa, vb[dg], O[qg][dg]);
      }
    }
  }

  // lsum: per-lane partial covers keys {quad*4+r, +16kg, +64kt} for q=qg*16+lq;
  // reduce over quads -> every lane holds full l for q=qg*16+lq
  float inv[4];
#pragma unroll
  for (int qg = 0; qg < 4; ++qg) {
    float l = lsum[qg];
    l += __shfl_xor(l, 16, 64);
    l += __shfl_xor(l, 32, 64);
    inv[qg] = 1.f / l;
  }

  // epilogue: O C-layout: q = qg*16+quad*4+r (row), d = dg*16+lq (col)
#pragma unroll
  for (int qg = 0; qg < 4; ++qg) {
#pragma unroll
    for (int r = 0; r < 4; ++r) {
      const float iv = __shfl(inv[qg], quad * 4 + r, 64);
      const size_t trow = (size_t)(qt * 256 + w * 64 + qg * 16 + quad * 4 + r);
      float* op = out + ((size_t)b * 2048 + trow) * 1024 + h * 64 + lq;
#pragma unroll
      for (int dg = 0; dg < 4; ++dg) op[dg * 16] = O[qg][dg][r] * iv;
    }
  }
}

extern "C" void kernel_launch(void* const* d_in, const int* in_sizes, int n_in,
                              void* d_out, int out_size, void* d_ws, size_t ws_size,
                              hipStream_t stream) {
  (void)in_sizes; (void)n_in; (void)out_size; (void)ws_size;
  const float* x = (const float*)d_in[0];
  const float* Wq = (const float*)d_in[1];
  const float* Wk = (const float*)d_in[2];
  const float* Wv = (const float*)d_in[3];
  const float* wip = (const float*)d_in[4];
  float* out = (float*)d_out;

  u16* xb = (u16*)d_ws;
  u16* wb = xb + 8388608;
  u16* qb = wb + 3145728;
  u16* kb = qb + 8388608;
  u16* vb = kb + 8388608;   // holds V^T [B][H][64][2048]

  cvt_all<<<11264, 256, 0, stream>>>(x, Wq, Wk, Wv, xb, wb);
  qkv_gemm<<<dim3(64, 8, 3), 256, 0, stream>>>(xb, wb, qb);
  palace_attn<<<dim3(64, 8, 1), 256, 0, stream>>>(qb, kb, vb, out, wip);
}